// Round 5
// baseline (464.662 us; speedup 1.0000x reference)
//
#include <hip/hip_runtime.h>

#define D_FEAT 64

typedef __attribute__((ext_vector_type(8))) short bf16x8;
typedef __attribute__((ext_vector_type(4))) float f32x4;

// ---------------- utility ----------------

__global__ void zero_int_kernel(int* __restrict__ p, int n) {
    int i = blockIdx.x * blockDim.x + threadIdx.x;
    if (i < n) p[i] = 0;
}

// count[d] += 1 per edge (int atomics)
__global__ void count_kernel(const int* __restrict__ dst, int* __restrict__ count, int e) {
    int i = blockIdx.x * blockDim.x + threadIdx.x;
    if (i < e) atomicAdd(&count[dst[i]], 1);
}

// dinv[i] = rsqrt(1 + indeg)
__global__ void dinv_kernel(const int* __restrict__ count, float* __restrict__ dinv, int n) {
    int i = blockIdx.x * blockDim.x + threadIdx.x;
    if (i < n) dinv[i] = rsqrtf(1.0f + (float)count[i]);
}

// ---------------- exclusive scan (3 kernels) ----------------

__global__ __launch_bounds__(256) void scan_block_kernel(const int* __restrict__ count,
                                                         int* __restrict__ rp,
                                                         int* __restrict__ bsum, int n) {
    __shared__ int s[256];
    int tid = threadIdx.x;
    int i = blockIdx.x * 256 + tid;
    int v = (i < n) ? count[i] : 0;
    s[tid] = v;
    __syncthreads();
    for (int off = 1; off < 256; off <<= 1) {
        int t = (tid >= off) ? s[tid - off] : 0;
        __syncthreads();
        s[tid] += t;
        __syncthreads();
    }
    if (i < n) rp[i] = s[tid] - v;  // exclusive
    if (tid == 255) bsum[blockIdx.x] = s[255];
}

__global__ void scan_sums_kernel(int* __restrict__ bsum, int nb) {
    if (blockIdx.x == 0 && threadIdx.x == 0) {
        int run = 0;
        for (int i = 0; i < nb; ++i) {
            int t = bsum[i];
            bsum[i] = run;
            run += t;
        }
    }
}

// finalize rp and write the working copy rpw (fill's atomic cursors)
__global__ __launch_bounds__(256) void scan_add_kernel(int* __restrict__ rp,
                                                       int* __restrict__ rpw,
                                                       const int* __restrict__ bsum,
                                                       int n, int e) {
    int i = blockIdx.x * 256 + threadIdx.x;
    if (i < n) {
        int v = rp[i] + bsum[i >> 8];
        rp[i] = v;
        rpw[i] = v;
    }
    if (i == 0) rp[n] = e;
}

// ---------------- CSR fill: col only (4B/edge scattered) ----------------

__global__ void fill_kernel(const int* __restrict__ src, const int* __restrict__ dst,
                            int* __restrict__ rpw, int* __restrict__ col, int e) {
    int i = blockIdx.x * blockDim.x + threadIdx.x;
    if (i >= e) return;
    int pos = atomicAdd(&rpw[dst[i]], 1);
    col[pos] = src[i];
}

// ---------------- hop 1: g1[d] = dinv[d]^2 * ( dinv[d]*x[d] + sum_e dinv[s]*x[s] ) ----------------
// 16 lanes per node, float4 per lane.

__global__ __launch_bounds__(256) void spmm_hop1_kernel(const int* __restrict__ rp,
                                                        const int* __restrict__ col,
                                                        const float* __restrict__ dinv,
                                                        const float* __restrict__ x,
                                                        float* __restrict__ g1, int n) {
    int t = blockIdx.x * 256 + threadIdx.x;
    int node = t >> 4;
    int j = t & 15;
    if (node >= n) return;
    int e0 = rp[node];
    int e1 = rp[node + 1];
    float di = dinv[node];
    const float4* x4 = (const float4*)x;
    float4 v = x4[(size_t)node * 16 + j];
    float4 acc;
    acc.x = di * v.x; acc.y = di * v.y; acc.z = di * v.z; acc.w = di * v.w;
    for (int e = e0; e < e1; ++e) {
        int s = col[e];
        float w = dinv[s];
        float4 u = x4[(size_t)s * 16 + j];
        acc.x = fmaf(w, u.x, acc.x);
        acc.y = fmaf(w, u.y, acc.y);
        acc.z = fmaf(w, u.z, acc.z);
        acc.w = fmaf(w, u.w, acc.w);
    }
    float d2 = di * di;
    acc.x *= d2; acc.y *= d2; acc.z *= d2; acc.w *= d2;
    ((float4*)g1)[(size_t)node * 16 + j] = acc;
}

// ---------------- hop 2: h2[d] = dinv[d] * ( g1[d] + sum_e g1[s] ) ----------------

__global__ __launch_bounds__(256) void spmm_hop2_kernel(const int* __restrict__ rp,
                                                        const int* __restrict__ col,
                                                        const float* __restrict__ dinv,
                                                        const float* __restrict__ g1,
                                                        float* __restrict__ h2, int n) {
    int t = blockIdx.x * 256 + threadIdx.x;
    int node = t >> 4;
    int j = t & 15;
    if (node >= n) return;
    int e0 = rp[node];
    int e1 = rp[node + 1];
    float di = dinv[node];
    const float4* g4 = (const float4*)g1;
    float4 acc = g4[(size_t)node * 16 + j];
    for (int e = e0; e < e1; ++e) {
        int s = col[e];
        float4 u = g4[(size_t)s * 16 + j];
        acc.x += u.x; acc.y += u.y; acc.z += u.z; acc.w += u.w;
    }
    acc.x *= di; acc.y *= di; acc.z *= di; acc.w *= di;
    ((float4*)h2)[(size_t)node * 16 + j] = acc;
}

// ---------------- output GEMM via bf16 MFMA ----------------
// feats = [x | g1*sqrt(deg) | h2]  (h1 == g1/dinv reconstructed exactly)

#define WT_LD 200  // padded leading dim (bf16 elems)

static __device__ inline short f2bf(float f) {
    unsigned u = __float_as_uint(f);
    u += 0x7fffu + ((u >> 16) & 1u);  // round-to-nearest-even
    return (short)(u >> 16);
}

__global__ __launch_bounds__(256) void gemm_mfma_kernel(const float* __restrict__ x,
                                                        const float* __restrict__ g1,
                                                        const float* __restrict__ h2,
                                                        const int* __restrict__ count,
                                                        const float* __restrict__ W,
                                                        const float* __restrict__ b,
                                                        float* __restrict__ out, int n) {
    __shared__ short sWt[64 * WT_LD];  // 25.6 KB, sWt[c][k] = bf16(W[k][c])
    int tid = threadIdx.x;

    for (int i = tid; i < 192 * 64; i += 256) {
        int k = i >> 6;
        int c = i & 63;
        sWt[c * WT_LD + k] = f2bf(W[i]);
    }
    __syncthreads();

    int w = tid >> 6;        // wave 0..3
    int l = tid & 63;        // lane
    int lr = l & 15;         // A row / D col
    int lk = l >> 4;         // 0..3 -> k-subslice
    int rbase = blockIdx.x * 64 + w * 16;

    int node = rbase + lr;
    int node_ld = node < n ? node : (n - 1);
    float sdeg = sqrtf(1.0f + (float)count[node_ld]);  // h1 = g1 * sdeg

    f32x4 acc[4] = {{0.f, 0.f, 0.f, 0.f}, {0.f, 0.f, 0.f, 0.f},
                    {0.f, 0.f, 0.f, 0.f}, {0.f, 0.f, 0.f, 0.f}};

    const float* srcs[3] = {x, g1, h2};
#pragma unroll
    for (int kt = 0; kt < 6; ++kt) {
        const float* sp = srcs[kt >> 1];
        float sc = ((kt >> 1) == 1) ? sdeg : 1.0f;
        int kb = (kt & 1) * 32 + lk * 8;
        const float4* ap = (const float4*)(sp + (size_t)node_ld * D_FEAT + kb);
        float4 a0 = ap[0];
        float4 a1 = ap[1];
        bf16x8 af;
        af[0] = f2bf(a0.x * sc); af[1] = f2bf(a0.y * sc);
        af[2] = f2bf(a0.z * sc); af[3] = f2bf(a0.w * sc);
        af[4] = f2bf(a1.x * sc); af[5] = f2bf(a1.y * sc);
        af[6] = f2bf(a1.z * sc); af[7] = f2bf(a1.w * sc);
        int kg = kt * 32 + lk * 8;
#pragma unroll
        for (int nt = 0; nt < 4; ++nt) {
            int c = nt * 16 + lr;
            bf16x8 bf = *(const bf16x8*)&sWt[c * WT_LD + kg];
            acc[nt] = __builtin_amdgcn_mfma_f32_16x16x32_bf16(af, bf, acc[nt], 0, 0, 0);
        }
    }

#pragma unroll
    for (int nt = 0; nt < 4; ++nt) {
        int c = nt * 16 + lr;
        float bias = b[c];
#pragma unroll
        for (int i = 0; i < 4; ++i) {
            int row = rbase + lk * 4 + i;
            if (row < n) out[(size_t)row * D_FEAT + c] = acc[nt][i] + bias;
        }
    }
}

// ---------------- launch ----------------

static inline size_t align256(size_t x) { return (x + 255) & ~(size_t)255; }

extern "C" void kernel_launch(void* const* d_in, const int* in_sizes, int n_in,
                              void* d_out, int out_size, void* d_ws, size_t ws_size,
                              hipStream_t stream) {
    const float* x  = (const float*)d_in[0];
    const int*   ei = (const int*)d_in[1];
    const float* W  = (const float*)d_in[2];
    const float* b  = (const float*)d_in[3];
    float* out = (float*)d_out;

    int N = in_sizes[0] / D_FEAT;
    int E = in_sizes[1] / 2;
    const int* src = ei;
    const int* dst = ei + E;

    char* base = (char*)d_ws;
    size_t off = 0;
    int* count  = (int*)(base + off);   off = align256(off + (size_t)N * 4);
    int* rp     = (int*)(base + off);   off = align256(off + ((size_t)N + 1) * 4);
    int* rpw    = (int*)(base + off);   off = align256(off + (size_t)N * 4);
    int* bsum   = (int*)(base + off);   off = align256(off + 4096);
    float* dinv = (float*)(base + off); off = align256(off + (size_t)N * 4);
    int* col    = (int*)(base + off);   off = align256(off + (size_t)E * 4);
    float* g1   = (float*)(base + off); off = align256(off + (size_t)N * D_FEAT * 4);
    float* h2   = (float*)(base + off); off = align256(off + (size_t)N * D_FEAT * 4);

    const int BS = 256;
    int gN   = (N + BS - 1) / BS;
    int gE   = (E + BS - 1) / BS;
    int nb   = gN;
    int gN16 = (int)(((long long)N * 16 + BS - 1) / BS);
    int gGemm = (N + 63) / 64;

    zero_int_kernel<<<gN, BS, 0, stream>>>(count, N);
    count_kernel<<<gE, BS, 0, stream>>>(dst, count, E);
    dinv_kernel<<<gN, BS, 0, stream>>>(count, dinv, N);
    scan_block_kernel<<<nb, BS, 0, stream>>>(count, rp, bsum, N);
    scan_sums_kernel<<<1, 64, 0, stream>>>(bsum, nb);
    scan_add_kernel<<<gN, BS, 0, stream>>>(rp, rpw, bsum, N, E);
    fill_kernel<<<gE, BS, 0, stream>>>(src, dst, rpw, col, E);
    spmm_hop1_kernel<<<gN16, BS, 0, stream>>>(rp, col, dinv, x, g1, N);
    spmm_hop2_kernel<<<gN16, BS, 0, stream>>>(rp, col, dinv, g1, h2, N);
    gemm_mfma_kernel<<<gGemm, BS, 0, stream>>>(x, g1, h2, count, W, b, out, N);
}

// Round 6
// 287.834 us; speedup vs baseline: 1.6143x; 1.6143x over previous
//
#include <hip/hip_runtime.h>

#define D_FEAT 64
#define CHUNK 4096        // edges per chunk (NC = ceil(E/CHUNK) must be <= 512)
#define NBMAX 512         // max buckets (N <= 131072)
#define BNODES 256        // nodes per bucket

typedef __attribute__((ext_vector_type(8))) short bf16x8;
typedef __attribute__((ext_vector_type(4))) float f32x4;

// ---------------- P1: per-chunk bucket histogram (LDS-privatized) ----------------

__global__ __launch_bounds__(256) void hist_kernel(const int* __restrict__ dst,
                                                   int* __restrict__ hist,  // [nc][nb]
                                                   int e, int nb) {
    __shared__ int hs[NBMAX];
    int tid = threadIdx.x;
    for (int i = tid; i < nb; i += 256) hs[i] = 0;
    __syncthreads();
    int base = blockIdx.x * CHUNK;
    int end = min(base + CHUNK, e);
    for (int i = base + tid; i < end; i += 256)
        atomicAdd(&hs[dst[i] >> 8], 1);
    __syncthreads();
    for (int i = tid; i < nb; i += 256)
        hist[(size_t)blockIdx.x * nb + i] = hs[i];
}

// ---------------- K2a: per-bucket exclusive scan over chunks (in-place) + totals ----------------

__global__ __launch_bounds__(512) void colscan_kernel(int* __restrict__ hist,  // [nc][nb] -> pref
                                                      int* __restrict__ totals,
                                                      int nc, int nb) {
    __shared__ int s[512];
    int k = blockIdx.x;  // bucket
    int t = threadIdx.x;
    int v = (t < nc) ? hist[(size_t)t * nb + k] : 0;
    s[t] = v;
    __syncthreads();
    for (int off = 1; off < 512; off <<= 1) {
        int u = (t >= off) ? s[t - off] : 0;
        __syncthreads();
        s[t] += u;
        __syncthreads();
    }
    if (t < nc) hist[(size_t)t * nb + k] = s[t] - v;  // exclusive prefix
    if (t == nc - 1) totals[k] = s[t];                // inclusive last = total
}

// ---------------- K2b: scan bucket totals -> bucket bases; rp[N]=E ----------------

__global__ __launch_bounds__(512) void base_kernel(const int* __restrict__ totals,
                                                   int* __restrict__ bbase,
                                                   int* __restrict__ rp,
                                                   int nb, int n, int e) {
    __shared__ int s[512];
    int t = threadIdx.x;
    int v = (t < nb) ? totals[t] : 0;
    s[t] = v;
    __syncthreads();
    for (int off = 1; off < 512; off <<= 1) {
        int u = (t >= off) ? s[t - off] : 0;
        __syncthreads();
        s[t] += u;
        __syncthreads();
    }
    if (t < nb) bbase[t] = s[t] - v;
    if (t == 0) {
        bbase[nb] = e;
        rp[n] = e;
    }
}

// ---------------- P3: scatter (dst,src) pairs into bucket-contiguous order ----------------

__global__ __launch_bounds__(256) void scatter_kernel(const int* __restrict__ src,
                                                      const int* __restrict__ dst,
                                                      const int* __restrict__ pref,  // [nc][nb]
                                                      const int* __restrict__ bbase,
                                                      int2* __restrict__ pairs,
                                                      int e, int nb) {
    __shared__ int cur[NBMAX];
    int tid = threadIdx.x;
    int b = blockIdx.x;
    for (int i = tid; i < nb; i += 256)
        cur[i] = bbase[i] + pref[(size_t)b * nb + i];
    __syncthreads();
    int base = b * CHUNK;
    int end = min(base + CHUNK, e);
    for (int i = base + tid; i < end; i += 256) {
        int d = dst[i];
        int pos = atomicAdd(&cur[d >> 8], 1);
        pairs[pos] = make_int2(d, src[i]);
    }
}

// ---------------- P4: per-bucket CSR build (rp, dinv, col) ----------------

__global__ __launch_bounds__(256) void csr_kernel(const int2* __restrict__ pairs,
                                                  const int* __restrict__ bbase,
                                                  int* __restrict__ rp,
                                                  float* __restrict__ dinv,
                                                  int* __restrict__ col, int n) {
    __shared__ int cnt[BNODES];
    __shared__ int s[BNODES];
    __shared__ int cur[BNODES];
    int tid = threadIdx.x;
    int k = blockIdx.x;
    int node0 = k * BNODES;
    int e0 = bbase[k];
    int e1 = bbase[k + 1];
    cnt[tid] = 0;
    __syncthreads();
    for (int i = e0 + tid; i < e1; i += 256)
        atomicAdd(&cnt[pairs[i].x - node0], 1);
    __syncthreads();
    int v = cnt[tid];
    s[tid] = v;
    __syncthreads();
    for (int off = 1; off < 256; off <<= 1) {
        int u = (tid >= off) ? s[tid - off] : 0;
        __syncthreads();
        s[tid] += u;
        __syncthreads();
    }
    int excl = s[tid] - v;
    cur[tid] = e0 + excl;
    int node = node0 + tid;
    if (node < n) {
        rp[node] = e0 + excl;
        dinv[node] = rsqrtf(1.0f + (float)v);
    }
    __syncthreads();
    for (int i = e0 + tid; i < e1; i += 256) {
        int2 p = pairs[i];
        int pos = atomicAdd(&cur[p.x - node0], 1);
        col[pos] = p.y;
    }
}

// ---------------- hop 1: g1[d] = dinv[d]^2 * ( dinv[d]*x[d] + sum_e dinv[s]*x[s] ) ----------------

__global__ __launch_bounds__(256) void spmm_hop1_kernel(const int* __restrict__ rp,
                                                        const int* __restrict__ col,
                                                        const float* __restrict__ dinv,
                                                        const float* __restrict__ x,
                                                        float* __restrict__ g1, int n) {
    int t = blockIdx.x * 256 + threadIdx.x;
    int node = t >> 4;
    int j = t & 15;
    if (node >= n) return;
    int e0 = rp[node];
    int e1 = rp[node + 1];
    float di = dinv[node];
    const float4* x4 = (const float4*)x;
    float4 v = x4[(size_t)node * 16 + j];
    float4 acc;
    acc.x = di * v.x; acc.y = di * v.y; acc.z = di * v.z; acc.w = di * v.w;
    for (int e = e0; e < e1; ++e) {
        int s = col[e];
        float w = dinv[s];
        float4 u = x4[(size_t)s * 16 + j];
        acc.x = fmaf(w, u.x, acc.x);
        acc.y = fmaf(w, u.y, acc.y);
        acc.z = fmaf(w, u.z, acc.z);
        acc.w = fmaf(w, u.w, acc.w);
    }
    float d2 = di * di;
    acc.x *= d2; acc.y *= d2; acc.z *= d2; acc.w *= d2;
    ((float4*)g1)[(size_t)node * 16 + j] = acc;
}

// ---------------- hop 2: h2[d] = dinv[d] * ( g1[d] + sum_e g1[s] ) ----------------

__global__ __launch_bounds__(256) void spmm_hop2_kernel(const int* __restrict__ rp,
                                                        const int* __restrict__ col,
                                                        const float* __restrict__ dinv,
                                                        const float* __restrict__ g1,
                                                        float* __restrict__ h2, int n) {
    int t = blockIdx.x * 256 + threadIdx.x;
    int node = t >> 4;
    int j = t & 15;
    if (node >= n) return;
    int e0 = rp[node];
    int e1 = rp[node + 1];
    float di = dinv[node];
    const float4* g4 = (const float4*)g1;
    float4 acc = g4[(size_t)node * 16 + j];
    for (int e = e0; e < e1; ++e) {
        int s = col[e];
        float4 u = g4[(size_t)s * 16 + j];
        acc.x += u.x; acc.y += u.y; acc.z += u.z; acc.w += u.w;
    }
    acc.x *= di; acc.y *= di; acc.z *= di; acc.w *= di;
    ((float4*)h2)[(size_t)node * 16 + j] = acc;
}

// ---------------- output GEMM via bf16 MFMA ----------------
// feats = [x | g1/dinv | h2]  (h1 == g1*sqrt(deg) reconstructed)

#define WT_LD 200

static __device__ inline short f2bf(float f) {
    unsigned u = __float_as_uint(f);
    u += 0x7fffu + ((u >> 16) & 1u);  // RNE
    return (short)(u >> 16);
}

__global__ __launch_bounds__(256) void gemm_mfma_kernel(const float* __restrict__ x,
                                                        const float* __restrict__ g1,
                                                        const float* __restrict__ h2,
                                                        const float* __restrict__ dinv,
                                                        const float* __restrict__ W,
                                                        const float* __restrict__ b,
                                                        float* __restrict__ out, int n) {
    __shared__ short sWt[64 * WT_LD];
    int tid = threadIdx.x;

    for (int i = tid; i < 192 * 64; i += 256) {
        int k = i >> 6;
        int c = i & 63;
        sWt[c * WT_LD + k] = f2bf(W[i]);
    }
    __syncthreads();

    int w = tid >> 6;
    int l = tid & 63;
    int lr = l & 15;
    int lk = l >> 4;
    int rbase = blockIdx.x * 64 + w * 16;

    int node = rbase + lr;
    int node_ld = node < n ? node : (n - 1);
    float sdeg = 1.0f / dinv[node_ld];  // = sqrt(1+deg) within ulps

    f32x4 acc[4] = {{0.f, 0.f, 0.f, 0.f}, {0.f, 0.f, 0.f, 0.f},
                    {0.f, 0.f, 0.f, 0.f}, {0.f, 0.f, 0.f, 0.f}};

    const float* srcs[3] = {x, g1, h2};
#pragma unroll
    for (int kt = 0; kt < 6; ++kt) {
        const float* sp = srcs[kt >> 1];
        float sc = ((kt >> 1) == 1) ? sdeg : 1.0f;
        int kb = (kt & 1) * 32 + lk * 8;
        const float4* ap = (const float4*)(sp + (size_t)node_ld * D_FEAT + kb);
        float4 a0 = ap[0];
        float4 a1 = ap[1];
        bf16x8 af;
        af[0] = f2bf(a0.x * sc); af[1] = f2bf(a0.y * sc);
        af[2] = f2bf(a0.z * sc); af[3] = f2bf(a0.w * sc);
        af[4] = f2bf(a1.x * sc); af[5] = f2bf(a1.y * sc);
        af[6] = f2bf(a1.z * sc); af[7] = f2bf(a1.w * sc);
        int kg = kt * 32 + lk * 8;
#pragma unroll
        for (int nt = 0; nt < 4; ++nt) {
            int c = nt * 16 + lr;
            bf16x8 bf = *(const bf16x8*)&sWt[c * WT_LD + kg];
            acc[nt] = __builtin_amdgcn_mfma_f32_16x16x32_bf16(af, bf, acc[nt], 0, 0, 0);
        }
    }

#pragma unroll
    for (int nt = 0; nt < 4; ++nt) {
        int c = nt * 16 + lr;
        float bias = b[c];
#pragma unroll
        for (int i = 0; i < 4; ++i) {
            int row = rbase + lk * 4 + i;
            if (row < n) out[(size_t)row * D_FEAT + c] = acc[nt][i] + bias;
        }
    }
}

// ---------------- launch ----------------

static inline size_t align256(size_t x) { return (x + 255) & ~(size_t)255; }

extern "C" void kernel_launch(void* const* d_in, const int* in_sizes, int n_in,
                              void* d_out, int out_size, void* d_ws, size_t ws_size,
                              hipStream_t stream) {
    const float* x  = (const float*)d_in[0];
    const int*   ei = (const int*)d_in[1];
    const float* W  = (const float*)d_in[2];
    const float* b  = (const float*)d_in[3];
    float* out = (float*)d_out;

    int N = in_sizes[0] / D_FEAT;
    int E = in_sizes[1] / 2;
    const int* src = ei;
    const int* dst = ei + E;

    int NB = (N + BNODES - 1) / BNODES;   // 391 for N=100000 (<=512)
    int NC = (E + CHUNK - 1) / CHUNK;     // 391 for E=1.6M   (<=512)

    char* base = (char*)d_ws;
    size_t off = 0;
    int* rp      = (int*)(base + off);   off = align256(off + ((size_t)N + 1) * 4);
    float* dinv  = (float*)(base + off); off = align256(off + (size_t)N * 4);
    int* totals  = (int*)(base + off);   off = align256(off + (size_t)NBMAX * 4);
    int* bbase   = (int*)(base + off);   off = align256(off + (size_t)(NBMAX + 1) * 4);
    int* col     = (int*)(base + off);   off = align256(off + (size_t)E * 4);
    float* g1    = (float*)(base + off); off = align256(off + (size_t)N * D_FEAT * 4);
    float* h2    = (float*)(base + off); off = align256(off + (size_t)N * D_FEAT * 4);
    // transient build arrays aliased into h2's span (dead before hop2 writes h2):
    int2* pairs  = (int2*)h2;                            // E*8 bytes  (12.8 MB < 25.6 MB)
    int* hist    = (int*)((char*)h2 + align256((size_t)E * 8));  // NC*NB*4 (~0.6 MB)

    const int BS = 256;
    int gN16 = (int)(((long long)N * 16 + BS - 1) / BS);
    int gGemm = (N + 63) / 64;

    hist_kernel<<<NC, BS, 0, stream>>>(dst, hist, E, NB);
    colscan_kernel<<<NB, 512, 0, stream>>>(hist, totals, NC, NB);
    base_kernel<<<1, 512, 0, stream>>>(totals, bbase, rp, NB, N, E);
    scatter_kernel<<<NC, BS, 0, stream>>>(src, dst, hist, bbase, pairs, E, NB);
    csr_kernel<<<NB, BS, 0, stream>>>(pairs, bbase, rp, dinv, col, N);
    spmm_hop1_kernel<<<gN16, BS, 0, stream>>>(rp, col, dinv, x, g1, N);
    spmm_hop2_kernel<<<gN16, BS, 0, stream>>>(rp, col, dinv, g1, h2, N);
    gemm_mfma_kernel<<<gGemm, BS, 0, stream>>>(x, g1, h2, dinv, W, b, out, N);
}

// Round 9
// 217.345 us; speedup vs baseline: 2.1379x; 1.3243x over previous
//
#include <hip/hip_runtime.h>

#define D_FEAT 64
#define CHUNK 4096        // edges per chunk (NC = ceil(E/CHUNK) must be <= 512)
#define NBMAX 512         // max buckets (N <= 131072)
#define BNODES 256        // nodes per bucket

typedef __attribute__((ext_vector_type(8))) short bf16x8;
typedef __attribute__((ext_vector_type(4))) float f32x4;

static __device__ inline short f2bf(float f) {
    unsigned u = __float_as_uint(f);
    u += 0x7fffu + ((u >> 16) & 1u);  // RNE
    return (short)(u >> 16);
}

// unpack 8 bf16 (as uint4) and accumulate into fp32[8]
static __device__ inline void acc8(uint4 u, float* a) {
    a[0] += __uint_as_float(u.x << 16);
    a[1] += __uint_as_float(u.x & 0xffff0000u);
    a[2] += __uint_as_float(u.y << 16);
    a[3] += __uint_as_float(u.y & 0xffff0000u);
    a[4] += __uint_as_float(u.z << 16);
    a[5] += __uint_as_float(u.z & 0xffff0000u);
    a[6] += __uint_as_float(u.w << 16);
    a[7] += __uint_as_float(u.w & 0xffff0000u);
}

// pack fp32[8] * s -> 8 bf16 as uint4
static __device__ inline uint4 pack8(const float* a, float s) {
    uint4 r;
    r.x = (unsigned)(unsigned short)f2bf(a[0] * s) | ((unsigned)(unsigned short)f2bf(a[1] * s) << 16);
    r.y = (unsigned)(unsigned short)f2bf(a[2] * s) | ((unsigned)(unsigned short)f2bf(a[3] * s) << 16);
    r.z = (unsigned)(unsigned short)f2bf(a[4] * s) | ((unsigned)(unsigned short)f2bf(a[5] * s) << 16);
    r.w = (unsigned)(unsigned short)f2bf(a[6] * s) | ((unsigned)(unsigned short)f2bf(a[7] * s) << 16);
    return r;
}

// ---------------- P1: per-chunk bucket histogram (LDS-privatized) ----------------

__global__ __launch_bounds__(256) void hist_kernel(const int* __restrict__ dst,
                                                   int* __restrict__ hist,  // [nc][nb]
                                                   int e, int nb) {
    __shared__ int hs[NBMAX];
    int tid = threadIdx.x;
    for (int i = tid; i < nb; i += 256) hs[i] = 0;
    __syncthreads();
    int base = blockIdx.x * CHUNK;
    int end = min(base + CHUNK, e);
    for (int i = base + tid; i < end; i += 256)
        atomicAdd(&hs[dst[i] >> 8], 1);
    __syncthreads();
    for (int i = tid; i < nb; i += 256)
        hist[(size_t)blockIdx.x * nb + i] = hs[i];
}

// ---------------- K2a: per-bucket exclusive scan over chunks (in-place) + totals ----------------

__global__ __launch_bounds__(512) void colscan_kernel(int* __restrict__ hist,
                                                      int* __restrict__ totals,
                                                      int nc, int nb) {
    __shared__ int s[512];
    int k = blockIdx.x;  // bucket
    int t = threadIdx.x;
    int v = (t < nc) ? hist[(size_t)t * nb + k] : 0;
    s[t] = v;
    __syncthreads();
    for (int off = 1; off < 512; off <<= 1) {
        int u = (t >= off) ? s[t - off] : 0;
        __syncthreads();
        s[t] += u;
        __syncthreads();
    }
    if (t < nc) hist[(size_t)t * nb + k] = s[t] - v;  // exclusive prefix
    if (t == nc - 1) totals[k] = s[t];                // inclusive last = total
}

// ---------------- K2b: scan bucket totals -> bucket bases; rp[N]=E ----------------

__global__ __launch_bounds__(512) void base_kernel(const int* __restrict__ totals,
                                                   int* __restrict__ bbase,
                                                   int* __restrict__ rp,
                                                   int nb, int n, int e) {
    __shared__ int s[512];
    int t = threadIdx.x;
    int v = (t < nb) ? totals[t] : 0;
    s[t] = v;
    __syncthreads();
    for (int off = 1; off < 512; off <<= 1) {
        int u = (t >= off) ? s[t - off] : 0;
        __syncthreads();
        s[t] += u;
        __syncthreads();
    }
    if (t < nb) bbase[t] = s[t] - v;
    if (t == 0) {
        bbase[nb] = e;
        rp[n] = e;
    }
}

// ---------------- P3: scatter (dst,src) pairs into bucket-contiguous order ----------------

__global__ __launch_bounds__(256) void scatter_kernel(const int* __restrict__ src,
                                                      const int* __restrict__ dst,
                                                      const int* __restrict__ pref,
                                                      const int* __restrict__ bbase,
                                                      int2* __restrict__ pairs,
                                                      int e, int nb) {
    __shared__ int cur[NBMAX];
    int tid = threadIdx.x;
    int b = blockIdx.x;
    for (int i = tid; i < nb; i += 256)
        cur[i] = bbase[i] + pref[(size_t)b * nb + i];
    __syncthreads();
    int base = b * CHUNK;
    int end = min(base + CHUNK, e);
    for (int i = base + tid; i < end; i += 256) {
        int d = dst[i];
        int pos = atomicAdd(&cur[d >> 8], 1);
        pairs[pos] = make_int2(d, src[i]);
    }
}

// ---------------- P4: per-bucket CSR build (rp, dinv, col) ----------------

__global__ __launch_bounds__(256) void csr_kernel(const int2* __restrict__ pairs,
                                                  const int* __restrict__ bbase,
                                                  int* __restrict__ rp,
                                                  float* __restrict__ dinv,
                                                  int* __restrict__ col, int n) {
    __shared__ int cnt[BNODES];
    __shared__ int s[BNODES];
    __shared__ int cur[BNODES];
    int tid = threadIdx.x;
    int k = blockIdx.x;
    int node0 = k * BNODES;
    int e0 = bbase[k];
    int e1 = bbase[k + 1];
    cnt[tid] = 0;
    __syncthreads();
    for (int i = e0 + tid; i < e1; i += 256)
        atomicAdd(&cnt[pairs[i].x - node0], 1);
    __syncthreads();
    int v = cnt[tid];
    s[tid] = v;
    __syncthreads();
    for (int off = 1; off < 256; off <<= 1) {
        int u = (tid >= off) ? s[tid - off] : 0;
        __syncthreads();
        s[tid] += u;
        __syncthreads();
    }
    int excl = s[tid] - v;
    cur[tid] = e0 + excl;
    int node = node0 + tid;
    if (node < n) {
        rp[node] = e0 + excl;
        dinv[node] = rsqrtf(1.0f + (float)v);
    }
    __syncthreads();
    for (int i = e0 + tid; i < e1; i += 256) {
        int2 p = pairs[i];
        int pos = atomicAdd(&cur[p.x - node0], 1);
        col[pos] = p.y;
    }
}

// ---------------- convert: xb = bf16(x), xs = bf16(dinv*x) ----------------
// 8 lanes/node, 8 floats per lane

__global__ __launch_bounds__(256) void convert_kernel(const float* __restrict__ x,
                                                      const float* __restrict__ dinv,
                                                      uint4* __restrict__ xb,
                                                      uint4* __restrict__ xs, int n) {
    int t = blockIdx.x * 256 + threadIdx.x;
    int node = t >> 3;
    int j = t & 7;
    if (node >= n) return;
    const float4* x4 = (const float4*)x;
    float4 a0 = x4[(size_t)node * 16 + j * 2];
    float4 a1 = x4[(size_t)node * 16 + j * 2 + 1];
    float di = dinv[node];
    float a[8] = {a0.x, a0.y, a0.z, a0.w, a1.x, a1.y, a1.z, a1.w};
    size_t o = (size_t)node * 8 + j;
    xb[o] = pack8(a, 1.0f);
    xs[o] = pack8(a, di);
}

// ---------------- hop 1: row-sum of xs; h1b = bf16(di*acc), g1b = bf16(di^2*acc) ----------------

__global__ __launch_bounds__(256) void spmm_hop1_kernel(const int* __restrict__ rp,
                                                        const int* __restrict__ col,
                                                        const float* __restrict__ dinv,
                                                        const uint4* __restrict__ xs,
                                                        uint4* __restrict__ h1b,
                                                        uint4* __restrict__ g1b, int n) {
    int t = blockIdx.x * 256 + threadIdx.x;
    int node = t >> 3;
    int j = t & 7;
    if (node >= n) return;
    int e0 = rp[node];
    int e1 = rp[node + 1];
    float di = dinv[node];
    float a[8] = {0, 0, 0, 0, 0, 0, 0, 0};
    float c[8] = {0, 0, 0, 0, 0, 0, 0, 0};
    acc8(xs[(size_t)node * 8 + j], a);  // self term
    int e = e0;
    for (; e + 1 < e1; e += 2) {
        int s0 = col[e];
        int s1 = col[e + 1];
        uint4 u0 = xs[(size_t)s0 * 8 + j];
        uint4 u1 = xs[(size_t)s1 * 8 + j];
        acc8(u0, a);
        acc8(u1, c);
    }
    if (e < e1) acc8(xs[(size_t)col[e] * 8 + j], a);
#pragma unroll
    for (int i = 0; i < 8; ++i) a[i] += c[i];
    size_t o = (size_t)node * 8 + j;
    h1b[o] = pack8(a, di);
    g1b[o] = pack8(a, di * di);
}

// ---------------- hop 2: row-sum of g1b; h2b = bf16(di*acc) ----------------

__global__ __launch_bounds__(256) void spmm_hop2_kernel(const int* __restrict__ rp,
                                                        const int* __restrict__ col,
                                                        const float* __restrict__ dinv,
                                                        const uint4* __restrict__ g1b,
                                                        uint4* __restrict__ h2b, int n) {
    int t = blockIdx.x * 256 + threadIdx.x;
    int node = t >> 3;
    int j = t & 7;
    if (node >= n) return;
    int e0 = rp[node];
    int e1 = rp[node + 1];
    float di = dinv[node];
    float a[8] = {0, 0, 0, 0, 0, 0, 0, 0};
    float c[8] = {0, 0, 0, 0, 0, 0, 0, 0};
    acc8(g1b[(size_t)node * 8 + j], a);
    int e = e0;
    for (; e + 1 < e1; e += 2) {
        int s0 = col[e];
        int s1 = col[e + 1];
        uint4 u0 = g1b[(size_t)s0 * 8 + j];
        uint4 u1 = g1b[(size_t)s1 * 8 + j];
        acc8(u0, a);
        acc8(u1, c);
    }
    if (e < e1) acc8(g1b[(size_t)col[e] * 8 + j], a);
#pragma unroll
    for (int i = 0; i < 8; ++i) a[i] += c[i];
    h2b[(size_t)node * 8 + j] = pack8(a, di);
}

// ---------------- output GEMM via bf16 MFMA ----------------
// feats = [xb | h1b | h2b], all already bf16

#define WT_LD 200

__global__ __launch_bounds__(256) void gemm_mfma_kernel(const unsigned short* __restrict__ xb,
                                                        const unsigned short* __restrict__ h1b,
                                                        const unsigned short* __restrict__ h2b,
                                                        const float* __restrict__ W,
                                                        const float* __restrict__ b,
                                                        float* __restrict__ out, int n) {
    __shared__ short sWt[64 * WT_LD];
    int tid = threadIdx.x;

    for (int i = tid; i < 192 * 64; i += 256) {
        int k = i >> 6;
        int c = i & 63;
        sWt[c * WT_LD + k] = f2bf(W[i]);
    }
    __syncthreads();

    int w = tid >> 6;
    int l = tid & 63;
    int lr = l & 15;
    int lk = l >> 4;
    int rbase = blockIdx.x * 64 + w * 16;

    int node = rbase + lr;
    int node_ld = node < n ? node : (n - 1);

    f32x4 acc[4] = {{0.f, 0.f, 0.f, 0.f}, {0.f, 0.f, 0.f, 0.f},
                    {0.f, 0.f, 0.f, 0.f}, {0.f, 0.f, 0.f, 0.f}};

    const unsigned short* srcs[3] = {xb, h1b, h2b};
#pragma unroll
    for (int kt = 0; kt < 6; ++kt) {
        const unsigned short* sp = srcs[kt >> 1];
        int kb = (kt & 1) * 32 + lk * 8;
        bf16x8 af = *(const bf16x8*)(sp + (size_t)node_ld * D_FEAT + kb);
        int kg = kt * 32 + lk * 8;
#pragma unroll
        for (int nt = 0; nt < 4; ++nt) {
            int c = nt * 16 + lr;
            bf16x8 bf = *(const bf16x8*)&sWt[c * WT_LD + kg];
            acc[nt] = __builtin_amdgcn_mfma_f32_16x16x32_bf16(af, bf, acc[nt], 0, 0, 0);
        }
    }

#pragma unroll
    for (int nt = 0; nt < 4; ++nt) {
        int c = nt * 16 + lr;
        float bias = b[c];
#pragma unroll
        for (int i = 0; i < 4; ++i) {
            int row = rbase + lk * 4 + i;
            if (row < n) out[(size_t)row * D_FEAT + c] = acc[nt][i] + bias;
        }
    }
}

// ---------------- launch ----------------

static inline size_t align256(size_t x) { return (x + 255) & ~(size_t)255; }

extern "C" void kernel_launch(void* const* d_in, const int* in_sizes, int n_in,
                              void* d_out, int out_size, void* d_ws, size_t ws_size,
                              hipStream_t stream) {
    const float* x  = (const float*)d_in[0];
    const int*   ei = (const int*)d_in[1];
    const float* W  = (const float*)d_in[2];
    const float* b  = (const float*)d_in[3];
    float* out = (float*)d_out;

    int N = in_sizes[0] / D_FEAT;
    int E = in_sizes[1] / 2;
    const int* src = ei;
    const int* dst = ei + E;

    int NB = (N + BNODES - 1) / BNODES;   // 391 for N=100000 (<=512)
    int NC = (E + CHUNK - 1) / CHUNK;     // 391 for E=1.6M   (<=512)

    char* base = (char*)d_ws;
    size_t off = 0;
    int* rp      = (int*)(base + off);   off = align256(off + ((size_t)N + 1) * 4);
    float* dinv  = (float*)(base + off); off = align256(off + (size_t)N * 4);
    int* totals  = (int*)(base + off);   off = align256(off + (size_t)NBMAX * 4);
    int* bbase   = (int*)(base + off);   off = align256(off + (size_t)(NBMAX + 1) * 4);
    int* col     = (int*)(base + off);   off = align256(off + (size_t)E * 4);
    uint4* xb    = (uint4*)(base + off); off = align256(off + (size_t)N * D_FEAT * 2);
    uint4* xs    = (uint4*)(base + off); off = align256(off + (size_t)N * D_FEAT * 2);
    uint4* h1b   = (uint4*)(base + off); off = align256(off + (size_t)N * D_FEAT * 2);
    uint4* g1b   = (uint4*)(base + off); off = align256(off + (size_t)N * D_FEAT * 2);
    uint4* h2b   = (uint4*)(base + off); off = align256(off + (size_t)N * D_FEAT * 2);
    // transient build arrays aliased onto later-written spans:
    int2* pairs  = (int2*)(base + off);  // E*8 = 12.8 MB, dead after csr_kernel
    int* hist    = (int*)((char*)pairs + align256((size_t)E * 8));  // NC*NB*4, dead after scatter

    const int BS = 256;
    int gN8 = (int)(((long long)N * 8 + BS - 1) / BS);
    int gGemm = (N + 63) / 64;

    hist_kernel<<<NC, BS, 0, stream>>>(dst, hist, E, NB);
    colscan_kernel<<<NB, 512, 0, stream>>>(hist, totals, NC, NB);
    base_kernel<<<1, 512, 0, stream>>>(totals, bbase, rp, NB, N, E);
    scatter_kernel<<<NC, BS, 0, stream>>>(src, dst, hist, bbase, pairs, E, NB);
    csr_kernel<<<NB, BS, 0, stream>>>(pairs, bbase, rp, dinv, col, N);
    convert_kernel<<<gN8, BS, 0, stream>>>(x, dinv, xb, xs, N);
    spmm_hop1_kernel<<<gN8, BS, 0, stream>>>(rp, col, dinv, xs, h1b, g1b, N);
    spmm_hop2_kernel<<<gN8, BS, 0, stream>>>(rp, col, dinv, g1b, h2b, N);
    gemm_mfma_kernel<<<gGemm, BS, 0, stream>>>((const unsigned short*)xb,
                                               (const unsigned short*)h1b,
                                               (const unsigned short*)h2b,
                                               W, b, out, N);
}

// Round 11
// 217.318 us; speedup vs baseline: 2.1382x; 1.0001x over previous
//
#include <hip/hip_runtime.h>

#define D_FEAT 64
#define CHUNK 4096        // edges per chunk (NC = ceil(E/CHUNK) must be <= 512)
#define NBMAX 512         // max buckets (N <= 131072; also requires N < 2^24 for packing)
#define BNODES 256        // nodes per bucket

typedef __attribute__((ext_vector_type(8))) short bf16x8;
typedef __attribute__((ext_vector_type(4))) float f32x4;

static __device__ inline short f2bf(float f) {
    unsigned u = __float_as_uint(f);
    u += 0x7fffu + ((u >> 16) & 1u);  // RNE
    return (short)(u >> 16);
}

// unpack 8 bf16 (as uint4) and accumulate into fp32[8]
static __device__ inline void acc8(uint4 u, float* a) {
    a[0] += __uint_as_float(u.x << 16);
    a[1] += __uint_as_float(u.x & 0xffff0000u);
    a[2] += __uint_as_float(u.y << 16);
    a[3] += __uint_as_float(u.y & 0xffff0000u);
    a[4] += __uint_as_float(u.z << 16);
    a[5] += __uint_as_float(u.z & 0xffff0000u);
    a[6] += __uint_as_float(u.w << 16);
    a[7] += __uint_as_float(u.w & 0xffff0000u);
}

// pack fp32[8] * s -> 8 bf16 as uint4
static __device__ inline uint4 pack8(const float* a, float s) {
    uint4 r;
    r.x = (unsigned)(unsigned short)f2bf(a[0] * s) | ((unsigned)(unsigned short)f2bf(a[1] * s) << 16);
    r.y = (unsigned)(unsigned short)f2bf(a[2] * s) | ((unsigned)(unsigned short)f2bf(a[3] * s) << 16);
    r.z = (unsigned)(unsigned short)f2bf(a[4] * s) | ((unsigned)(unsigned short)f2bf(a[5] * s) << 16);
    r.w = (unsigned)(unsigned short)f2bf(a[6] * s) | ((unsigned)(unsigned short)f2bf(a[7] * s) << 16);
    return r;
}

// ---------------- P1: per-chunk bucket histogram (LDS-privatized) ----------------

__global__ __launch_bounds__(256) void hist_kernel(const int* __restrict__ dst,
                                                   int* __restrict__ hist,  // [nc][nb]
                                                   int e, int nb) {
    __shared__ int hs[NBMAX];
    int tid = threadIdx.x;
    for (int i = tid; i < nb; i += 256) hs[i] = 0;
    __syncthreads();
    int base = blockIdx.x * CHUNK;
    int end = min(base + CHUNK, e);
    for (int i = base + tid; i < end; i += 256)
        atomicAdd(&hs[dst[i] >> 8], 1);
    __syncthreads();
    for (int i = tid; i < nb; i += 256)
        hist[(size_t)blockIdx.x * nb + i] = hs[i];
}

// ---------------- K2a: per-bucket exclusive scan over chunks (in-place) + totals ----------------

__global__ __launch_bounds__(512) void colscan_kernel(int* __restrict__ hist,
                                                      int* __restrict__ totals,
                                                      int nc, int nb) {
    __shared__ int s[512];
    int k = blockIdx.x;  // bucket
    int t = threadIdx.x;
    int v = (t < nc) ? hist[(size_t)t * nb + k] : 0;
    s[t] = v;
    __syncthreads();
    for (int off = 1; off < 512; off <<= 1) {
        int u = (t >= off) ? s[t - off] : 0;
        __syncthreads();
        s[t] += u;
        __syncthreads();
    }
    if (t < nc) hist[(size_t)t * nb + k] = s[t] - v;  // exclusive prefix
    if (t == nc - 1) totals[k] = s[t];                // inclusive last = total
}

// ---------------- K2b: scan bucket totals -> bucket bases; rp[N]=E ----------------

__global__ __launch_bounds__(512) void base_kernel(const int* __restrict__ totals,
                                                   int* __restrict__ bbase,
                                                   int* __restrict__ rp,
                                                   int nb, int n, int e) {
    __shared__ int s[512];
    int t = threadIdx.x;
    int v = (t < nb) ? totals[t] : 0;
    s[t] = v;
    __syncthreads();
    for (int off = 1; off < 512; off <<= 1) {
        int u = (t >= off) ? s[t - off] : 0;
        __syncthreads();
        s[t] += u;
        __syncthreads();
    }
    if (t < nb) bbase[t] = s[t] - v;
    if (t == 0) {
        bbase[nb] = e;
        rp[n] = e;
    }
}

// ---------------- P3: scatter packed (dlocal,src) into bucket-contiguous order ----------------
// pack: (d & 255) << 24 | src   (requires src < 2^24, BNODES == 256)

__global__ __launch_bounds__(256) void scatter_kernel(const int* __restrict__ src,
                                                      const int* __restrict__ dst,
                                                      const int* __restrict__ pref,
                                                      const int* __restrict__ bbase,
                                                      unsigned* __restrict__ pairs,
                                                      int e, int nb) {
    __shared__ int cur[NBMAX];
    int tid = threadIdx.x;
    int b = blockIdx.x;
    for (int i = tid; i < nb; i += 256)
        cur[i] = bbase[i] + pref[(size_t)b * nb + i];
    __syncthreads();
    int base = b * CHUNK;
    int end = min(base + CHUNK, e);
    for (int i = base + tid; i < end; i += 256) {
        int d = dst[i];
        int pos = atomicAdd(&cur[d >> 8], 1);
        pairs[pos] = ((unsigned)(d & 255) << 24) | (unsigned)src[i];
    }
}

// ---------------- P4: per-bucket CSR build (rp, dinv, col) ----------------

__global__ __launch_bounds__(256) void csr_kernel(const unsigned* __restrict__ pairs,
                                                  const int* __restrict__ bbase,
                                                  int* __restrict__ rp,
                                                  float* __restrict__ dinv,
                                                  int* __restrict__ col, int n) {
    __shared__ int cnt[BNODES];
    __shared__ int s[BNODES];
    __shared__ int cur[BNODES];
    int tid = threadIdx.x;
    int k = blockIdx.x;
    int node0 = k * BNODES;
    int e0 = bbase[k];
    int e1 = bbase[k + 1];
    cnt[tid] = 0;
    __syncthreads();
    for (int i = e0 + tid; i < e1; i += 256)
        atomicAdd(&cnt[pairs[i] >> 24], 1);
    __syncthreads();
    int v = cnt[tid];
    s[tid] = v;
    __syncthreads();
    for (int off = 1; off < 256; off <<= 1) {
        int u = (tid >= off) ? s[tid - off] : 0;
        __syncthreads();
        s[tid] += u;
        __syncthreads();
    }
    int excl = s[tid] - v;
    cur[tid] = e0 + excl;
    int node = node0 + tid;
    if (node < n) {
        rp[node] = e0 + excl;
        dinv[node] = rsqrtf(1.0f + (float)v);
    }
    __syncthreads();
    for (int i = e0 + tid; i < e1; i += 256) {
        unsigned p = pairs[i];
        int pos = atomicAdd(&cur[p >> 24], 1);
        col[pos] = (int)(p & 0xFFFFFFu);
    }
}

// ---------------- convert: xb = bf16(x), xs = bf16(dinv*x) ----------------
// 8 lanes/node, 8 floats per lane

__global__ __launch_bounds__(256) void convert_kernel(const float* __restrict__ x,
                                                      const float* __restrict__ dinv,
                                                      uint4* __restrict__ xb,
                                                      uint4* __restrict__ xs, int n) {
    int t = blockIdx.x * 256 + threadIdx.x;
    int node = t >> 3;
    int j = t & 7;
    if (node >= n) return;
    const float4* x4 = (const float4*)x;
    float4 a0 = x4[(size_t)node * 16 + j * 2];
    float4 a1 = x4[(size_t)node * 16 + j * 2 + 1];
    float di = dinv[node];
    float a[8] = {a0.x, a0.y, a0.z, a0.w, a1.x, a1.y, a1.z, a1.w};
    size_t o = (size_t)node * 8 + j;
    xb[o] = pack8(a, 1.0f);
    xs[o] = pack8(a, di);
}

// ---------------- hop 1: row-sum of xs; g1b = bf16(di^2*acc)  (h1 reconstructed in GEMM) ----------------

__global__ __launch_bounds__(256) void spmm_hop1_kernel(const int* __restrict__ rp,
                                                        const int* __restrict__ col,
                                                        const float* __restrict__ dinv,
                                                        const uint4* __restrict__ xs,
                                                        uint4* __restrict__ g1b, int n) {
    int t = blockIdx.x * 256 + threadIdx.x;
    int node = t >> 3;
    int j = t & 7;
    if (node >= n) return;
    int e0 = rp[node];
    int e1 = rp[node + 1];
    float di = dinv[node];
    float a[8] = {0, 0, 0, 0, 0, 0, 0, 0};
    float c[8] = {0, 0, 0, 0, 0, 0, 0, 0};
    acc8(xs[(size_t)node * 8 + j], a);  // self term
    int e = e0;
    for (; e + 3 < e1; e += 4) {
        int s0 = col[e];
        int s1 = col[e + 1];
        int s2 = col[e + 2];
        int s3 = col[e + 3];
        uint4 u0 = xs[(size_t)s0 * 8 + j];
        uint4 u1 = xs[(size_t)s1 * 8 + j];
        uint4 u2 = xs[(size_t)s2 * 8 + j];
        uint4 u3 = xs[(size_t)s3 * 8 + j];
        acc8(u0, a);
        acc8(u1, c);
        acc8(u2, a);
        acc8(u3, c);
    }
    for (; e < e1; ++e) acc8(xs[(size_t)col[e] * 8 + j], a);
#pragma unroll
    for (int i = 0; i < 8; ++i) a[i] += c[i];
    g1b[(size_t)node * 8 + j] = pack8(a, di * di);
}

// ---------------- hop 2: row-sum of g1b; h2b = bf16(di*acc) ----------------

__global__ __launch_bounds__(256) void spmm_hop2_kernel(const int* __restrict__ rp,
                                                        const int* __restrict__ col,
                                                        const float* __restrict__ dinv,
                                                        const uint4* __restrict__ g1b,
                                                        uint4* __restrict__ h2b, int n) {
    int t = blockIdx.x * 256 + threadIdx.x;
    int node = t >> 3;
    int j = t & 7;
    if (node >= n) return;
    int e0 = rp[node];
    int e1 = rp[node + 1];
    float di = dinv[node];
    float a[8] = {0, 0, 0, 0, 0, 0, 0, 0};
    float c[8] = {0, 0, 0, 0, 0, 0, 0, 0};
    acc8(g1b[(size_t)node * 8 + j], a);
    int e = e0;
    for (; e + 3 < e1; e += 4) {
        int s0 = col[e];
        int s1 = col[e + 1];
        int s2 = col[e + 2];
        int s3 = col[e + 3];
        uint4 u0 = g1b[(size_t)s0 * 8 + j];
        uint4 u1 = g1b[(size_t)s1 * 8 + j];
        uint4 u2 = g1b[(size_t)s2 * 8 + j];
        uint4 u3 = g1b[(size_t)s3 * 8 + j];
        acc8(u0, a);
        acc8(u1, c);
        acc8(u2, a);
        acc8(u3, c);
    }
    for (; e < e1; ++e) acc8(g1b[(size_t)col[e] * 8 + j], a);
#pragma unroll
    for (int i = 0; i < 8; ++i) a[i] += c[i];
    h2b[(size_t)node * 8 + j] = pack8(a, di);
}

// ---------------- output GEMM via bf16 MFMA, dual accumulator ----------------
// out = x@W0 + diag(sdeg)*(g1@W1) + h2@W2 + b, sdeg = 1/dinv (exact h1 reconstruction)

#define WT_LD 200

__global__ __launch_bounds__(256) void gemm_mfma_kernel(const unsigned short* __restrict__ xb,
                                                        const unsigned short* __restrict__ g1b,
                                                        const unsigned short* __restrict__ h2b,
                                                        const float* __restrict__ dinv,
                                                        const float* __restrict__ W,
                                                        const float* __restrict__ b,
                                                        float* __restrict__ out, int n) {
    __shared__ short sWt[64 * WT_LD];
    int tid = threadIdx.x;

    for (int i = tid; i < 192 * 64; i += 256) {
        int k = i >> 6;
        int c = i & 63;
        sWt[c * WT_LD + k] = f2bf(W[i]);
    }
    __syncthreads();

    int w = tid >> 6;
    int l = tid & 63;
    int lr = l & 15;
    int lk = l >> 4;
    int rbase = blockIdx.x * 64 + w * 16;

    int node = rbase + lr;
    int node_ld = node < n ? node : (n - 1);

    f32x4 accA[4] = {{0.f, 0.f, 0.f, 0.f}, {0.f, 0.f, 0.f, 0.f},
                     {0.f, 0.f, 0.f, 0.f}, {0.f, 0.f, 0.f, 0.f}};
    f32x4 accB[4] = {{0.f, 0.f, 0.f, 0.f}, {0.f, 0.f, 0.f, 0.f},
                     {0.f, 0.f, 0.f, 0.f}, {0.f, 0.f, 0.f, 0.f}};

    const unsigned short* srcs[3] = {xb, g1b, h2b};
#pragma unroll
    for (int kt = 0; kt < 6; ++kt) {
        const unsigned short* sp = srcs[kt >> 1];
        int kb = (kt & 1) * 32 + lk * 8;
        bf16x8 af = *(const bf16x8*)(sp + (size_t)node_ld * D_FEAT + kb);
        int kg = kt * 32 + lk * 8;
#pragma unroll
        for (int nt = 0; nt < 4; ++nt) {
            int c = nt * 16 + lr;
            bf16x8 bf = *(const bf16x8*)&sWt[c * WT_LD + kg];
            if ((kt >> 1) == 1)
                accB[nt] = __builtin_amdgcn_mfma_f32_16x16x32_bf16(af, bf, accB[nt], 0, 0, 0);
            else
                accA[nt] = __builtin_amdgcn_mfma_f32_16x16x32_bf16(af, bf, accA[nt], 0, 0, 0);
        }
    }

    // per-row sdeg for the 4 output rows this lane writes
    float sd[4];
#pragma unroll
    for (int i = 0; i < 4; ++i) {
        int row = rbase + lk * 4 + i;
        sd[i] = (row < n) ? (1.0f / dinv[row]) : 0.0f;
    }

#pragma unroll
    for (int nt = 0; nt < 4; ++nt) {
        int c = nt * 16 + lr;
        float bias = b[c];
#pragma unroll
        for (int i = 0; i < 4; ++i) {
            int row = rbase + lk * 4 + i;
            if (row < n)
                out[(size_t)row * D_FEAT + c] = accA[nt][i] + sd[i] * accB[nt][i] + bias;
        }
    }
}

// ---------------- launch ----------------

static inline size_t align256(size_t x) { return (x + 255) & ~(size_t)255; }

extern "C" void kernel_launch(void* const* d_in, const int* in_sizes, int n_in,
                              void* d_out, int out_size, void* d_ws, size_t ws_size,
                              hipStream_t stream) {
    const float* x  = (const float*)d_in[0];
    const int*   ei = (const int*)d_in[1];
    const float* W  = (const float*)d_in[2];
    const float* b  = (const float*)d_in[3];
    float* out = (float*)d_out;

    int N = in_sizes[0] / D_FEAT;
    int E = in_sizes[1] / 2;
    const int* src = ei;
    const int* dst = ei + E;

    int NB = (N + BNODES - 1) / BNODES;   // 391 for N=100000 (<=512)
    int NC = (E + CHUNK - 1) / CHUNK;     // 391 for E=1.6M   (<=512)

    char* base = (char*)d_ws;
    size_t off = 0;
    int* rp      = (int*)(base + off);   off = align256(off + ((size_t)N + 1) * 4);
    float* dinv  = (float*)(base + off); off = align256(off + (size_t)N * 4);
    int* totals  = (int*)(base + off);   off = align256(off + (size_t)NBMAX * 4);
    int* bbase   = (int*)(base + off);   off = align256(off + (size_t)(NBMAX + 1) * 4);
    int* col     = (int*)(base + off);   off = align256(off + (size_t)E * 4);
    uint4* xb    = (uint4*)(base + off); off = align256(off + (size_t)N * D_FEAT * 2);
    uint4* xs    = (uint4*)(base + off); off = align256(off + (size_t)N * D_FEAT * 2);
    uint4* g1b   = (uint4*)(base + off); off = align256(off + (size_t)N * D_FEAT * 2);
    uint4* h2b   = (uint4*)(base + off); off = align256(off + (size_t)N * D_FEAT * 2);
    // transient build arrays beyond the persistent spans:
    unsigned* pairs = (unsigned*)(base + off);  // E*4 = 6.4 MB, dead after csr_kernel
    int* hist    = (int*)((char*)pairs + align256((size_t)E * 4));  // NC*NB*4, dead after scatter

    const int BS = 256;
    int gN8 = (int)(((long long)N * 8 + BS - 1) / BS);
    int gGemm = (N + 63) / 64;

    hist_kernel<<<NC, BS, 0, stream>>>(dst, hist, E, NB);
    colscan_kernel<<<NB, 512, 0, stream>>>(hist, totals, NC, NB);
    base_kernel<<<1, 512, 0, stream>>>(totals, bbase, rp, NB, N, E);
    scatter_kernel<<<NC, BS, 0, stream>>>(src, dst, hist, bbase, pairs, E, NB);
    csr_kernel<<<NB, BS, 0, stream>>>(pairs, bbase, rp, dinv, col, N);
    convert_kernel<<<gN8, BS, 0, stream>>>(x, dinv, xb, xs, N);
    spmm_hop1_kernel<<<gN8, BS, 0, stream>>>(rp, col, dinv, xs, g1b, N);
    spmm_hop2_kernel<<<gN8, BS, 0, stream>>>(rp, col, dinv, g1b, h2b, N);
    gemm_mfma_kernel<<<gGemm, BS, 0, stream>>>((const unsigned short*)xb,
                                               (const unsigned short*)g1b,
                                               (const unsigned short*)h2b,
                                               dinv, W, b, out, N);
}